// Round 9
// baseline (692.035 us; speedup 1.0000x reference)
//
#include <hip/hip_runtime.h>

// Round 9: LDS-free direct-fragment GEMM. A[M][K] and Bt[N][K] fragment
// layouts are 16B/lane-contiguous, so MFMA operands load straight from
// global (L1/L2-cached) with register ping-pong prefetch; no __syncthreads,
// no vmcnt(0) barrier drain (the m97-structure staller at short K).
// Attention (R8 split-K + XCD swizzle) unchanged.

typedef __bf16 bf16;
typedef __bf16 bf16x8 __attribute__((ext_vector_type(8)));
typedef float f32x4 __attribute__((ext_vector_type(4)));

#define NROWS 4096   // B*S
#define DM 1024
#define SEQ 2048
#define NHEAD 16
#define DKH 64
#define DFF 4096
#define QSCALE 0.18033688f   // 0.125 * log2(e), folded into Q at QKV epilogue

// ---------------- private scratch (allocated at dlopen, NOT inside kernel_launch) ----
static char* g_scratch = nullptr;
namespace {
struct ScratchInit {
  ScratchInit() {
    void* p = nullptr;
    if (hipMalloc(&p, (size_t)128 * 1024 * 1024) == hipSuccess) g_scratch = (char*)p;
  }
};
static ScratchInit g_scratch_init;
}

// ---------------- LayerNorm (fp32 in, bf16 out) ----------------
__global__ __launch_bounds__(256) void ln_kernel(const float* __restrict__ inp,
                                                 const float* __restrict__ gamma,
                                                 const float* __restrict__ beta,
                                                 bf16* __restrict__ out) {
  int row = blockIdx.x;
  int t = threadIdx.x;
  float4 xv = *((const float4*)(inp + (size_t)row * DM) + t);
  float v[4] = {xv.x, xv.y, xv.z, xv.w};
  float s = 0.f, sq = 0.f;
#pragma unroll
  for (int i = 0; i < 4; i++) { s += v[i]; sq += v[i] * v[i]; }
#pragma unroll
  for (int m = 32; m >= 1; m >>= 1) { s += __shfl_xor(s, m); sq += __shfl_xor(sq, m); }
  __shared__ float rs[4], rq[4];
  int w = t >> 6, lane = t & 63;
  if (lane == 0) { rs[w] = s; rq[w] = sq; }
  __syncthreads();
  s = rs[0] + rs[1] + rs[2] + rs[3];
  sq = rq[0] + rq[1] + rq[2] + rq[3];
  float mu = s * (1.f / DM);
  float var = sq * (1.f / DM) - mu * mu;
  float rinv = rsqrtf(var + 1e-5f);
  float4 gv = *((const float4*)gamma + t);
  float4 bv = *((const float4*)beta + t);
  float g[4] = {gv.x, gv.y, gv.z, gv.w}, b[4] = {bv.x, bv.y, bv.z, bv.w};
  bf16 ov[4];
#pragma unroll
  for (int i = 0; i < 4; i++) ov[i] = (bf16)((v[i] - mu) * rinv * g[i] + b[i]);
  *(uint2*)(out + (size_t)row * DM + t * 4) = *(uint2*)ov;
}

// ---------------- bias concat (bq|bk|bv -> 3072 floats) ----------------
__global__ __launch_bounds__(256) void concat_bias(const float* __restrict__ bq,
                                                   const float* __restrict__ bk,
                                                   const float* __restrict__ bv,
                                                   float* __restrict__ cat) {
  int i = blockIdx.x * 256 + threadIdx.x;
  float v = (i < 1024) ? bq[i] : (i < 2048 ? bk[i - 1024] : bv[i - 2048]);
  cat[i] = v;
}

// ---------------- Transpose fp32 [R][C] -> bf16 [C][R] ----------------
__global__ __launch_bounds__(1024) void transpose_f32_bf16(const float* __restrict__ in,
                                                           bf16* __restrict__ out,
                                                           int R, int C) {
  __shared__ bf16 tile[32][33];
  int x = blockIdx.x * 32 + threadIdx.x;
  int y = blockIdx.y * 32 + threadIdx.y;
  tile[threadIdx.y][threadIdx.x] = (bf16)in[(size_t)y * C + x];
  __syncthreads();
  int ox = blockIdx.y * 32 + threadIdx.x;
  int oy = blockIdx.x * 32 + threadIdx.y;
  out[(size_t)oy * R + ox] = tile[threadIdx.x][threadIdx.y];
}

// ---------------- Transpose bf16 [R][C] -> bf16 [C][R] (for V) ----------------
__global__ __launch_bounds__(1024) void transpose_bf16(const bf16* __restrict__ in,
                                                       bf16* __restrict__ out,
                                                       int R, int C) {
  __shared__ bf16 tile[32][33];
  size_t zoff = (size_t)blockIdx.z * (size_t)R * (size_t)C;
  int x = blockIdx.x * 32 + threadIdx.x;
  int y = blockIdx.y * 32 + threadIdx.y;
  tile[threadIdx.y][threadIdx.x] = in[zoff + (size_t)y * C + x];
  __syncthreads();
  int ox = blockIdx.y * 32 + threadIdx.x;
  int oy = blockIdx.x * 32 + threadIdx.y;
  out[zoff + (size_t)oy * R + ox] = tile[threadIdx.x][threadIdx.y];
}

// ---------------- GEMM: C[M][N] = A[M][K] * Bt[N][K]^T + bias, fused epilogues ----------
// LDS-free: MFMA fragments loaded directly from global (16B/lane), register
// ping-pong prefetch of the next 64-K slice. No barriers in the K-loop.
#define BM 128

#define EPI_QKV3 0      // fused QKV: bf16 scatter to [B,H,S,DKH] x3, Q scaled by QSCALE
#define EPI_ATTN_RES 1  // outf fp32 = acc + bias + add (x fp32)
#define EPI_GELU 2      // outb bf16 = gelu(acc + bias)
#define EPI_FFN2 3      // outf fp32 = acc + bias + add (res fp32)

// BNT = 128: waves 2x2 (64x64 each). BNT = 64: waves 4x1 (32x64).
template<int EPI, int BNT>
__global__ __launch_bounds__(256, 2) void gemm_bt(
    const bf16* __restrict__ A, const bf16* __restrict__ Bt,
    const float* __restrict__ bias, int Kd, int N,
    bf16* __restrict__ outb, float* __restrict__ outf,
    const float* __restrict__ add) {
  constexpr int MS = (BNT == 128) ? 4 : 2;
  int t = threadIdx.x;
  int m0 = blockIdx.y * BM, n0 = blockIdx.x * BNT;
  int w = t >> 6, lane = t & 63, ln = lane & 15, quad = lane >> 4;
  int wm = (BNT == 128) ? (w >> 1) * 64 : w * 32;
  int wn = (BNT == 128) ? (w & 1) * 64 : 0;
  f32x4 acc[MS][4];
#pragma unroll
  for (int i = 0; i < MS; i++)
#pragma unroll
    for (int j = 0; j < 4; j++) acc[i][j] = (f32x4){0.f, 0.f, 0.f, 0.f};

  const bf16* Ab = A + (size_t)(m0 + wm + ln) * Kd + quad * 8;
  const bf16* Bb = Bt + (size_t)(n0 + wn + ln) * Kd + quad * 8;

  bf16x8 a0[MS][2], b0[4][2], a1[MS][2], b1[4][2];

#define LOAD_A(dst, k)                                                        \
  {                                                                           \
    _Pragma("unroll") for (int ms = 0; ms < MS; ms++)                         \
        _Pragma("unroll") for (int ks = 0; ks < 2; ks++)                      \
            dst[ms][ks] = *(const bf16x8*)(Ab + (size_t)(ms * 16) * Kd + (k) + ks * 32); \
  }
#define LOAD_B(dst, k)                                                        \
  {                                                                           \
    _Pragma("unroll") for (int ns = 0; ns < 4; ns++)                          \
        _Pragma("unroll") for (int ks = 0; ks < 2; ks++)                      \
            dst[ns][ks] = *(const bf16x8*)(Bb + (size_t)(ns * 16) * Kd + (k) + ks * 32); \
  }
#define MFMA_STEP(af, bf)                                                     \
  {                                                                           \
    _Pragma("unroll") for (int ms = 0; ms < MS; ms++)                         \
        _Pragma("unroll") for (int ns = 0; ns < 4; ns++)                      \
            _Pragma("unroll") for (int ks = 0; ks < 2; ks++)                  \
                acc[ms][ns] = __builtin_amdgcn_mfma_f32_16x16x32_bf16(        \
                    af[ms][ks], bf[ns][ks], acc[ms][ns], 0, 0, 0);            \
  }

  LOAD_A(a0, 0);
  LOAD_B(b0, 0);
  for (int k0 = 0; k0 < Kd; k0 += 128) {
    LOAD_A(a1, k0 + 64);
    LOAD_B(b1, k0 + 64);
    MFMA_STEP(a0, b0);
    if (k0 + 128 < Kd) {
      LOAD_A(a0, k0 + 128);
      LOAD_B(b0, k0 + 128);
    }
    MFMA_STEP(a1, b1);
  }
#undef LOAD_A
#undef LOAD_B
#undef MFMA_STEP

#pragma unroll
  for (int ms = 0; ms < MS; ms++) {
#pragma unroll
    for (int ns = 0; ns < 4; ns++) {
      int col = n0 + wn + ns * 16 + ln;
      float bv = bias[col];
#pragma unroll
      for (int r = 0; r < 4; r++) {
        int row = m0 + wm + ms * 16 + quad * 4 + r;
        float val = acc[ms][ns][r] + bv;
        if (EPI == EPI_QKV3) {
          int which = col >> 10, cc = col & 1023;
          int h = cc >> 6, dk = cc & 63;
          float sc = (which == 0) ? QSCALE : 1.f;
          int b = row >> 11, sx = row & 2047;
          outb[(size_t)which * (4 << 20) +
               ((((size_t)b * NHEAD + h) * SEQ) + sx) * DKH + dk] = (bf16)(val * sc);
        } else if (EPI == EPI_ATTN_RES) {
          size_t idx = (size_t)row * DM + col;
          outf[idx] = val + add[idx];
        } else if (EPI == EPI_GELU) {
          float gl = 0.5f * val * (1.f + erff(val * 0.7071067811865475f));
          outb[(size_t)row * N + col] = (bf16)gl;
        } else {
          size_t idx = (size_t)row * DM + col;
          outf[idx] = val + add[idx];
        }
      }
    }
  }
}

// ---------------- Flash attention, split-K, XCD-swizzled, 2-pass combine (R8) ----------
#define LSTR 72
#define OSTR 68   // fp32 combine row stride (2-way conflicts only)

__global__ __launch_bounds__(256) void attn_kernel(
    const bf16* __restrict__ Q, const bf16* __restrict__ K,
    const bf16* __restrict__ Vt, bf16* __restrict__ out) {
  __shared__ float smem[4608];  // 18432 B: max(P 4*32*72*2B, Ob 2*32*68*4B + Lb 512B)
  int lin = blockIdx.x;
  int bh = lin & 31;
  int qq = 63 - (lin >> 5);            // LPT: heaviest first
  int t = threadIdx.x, w = t >> 6, lane = t & 63, ln = lane & 15, quad = lane >> 4;
  int qbase = qq * 32;
  size_t bhS = (size_t)bh * SEQ;
  const bf16* Vg0 = Vt + (size_t)bh * DKH * SEQ;
  bf16* Pw = (bf16*)smem + w * 32 * LSTR;   // per-wave P slice (loop only)

  bf16x8 qa[2][2];
#pragma unroll
  for (int m = 0; m < 2; m++)
#pragma unroll
    for (int ks = 0; ks < 2; ks++)
      qa[m][ks] = *(const bf16x8*)(Q + (bhS + qbase + m * 16 + ln) * DKH + ks * 32 + quad * 8);

  bf16x8 ones;
#pragma unroll
  for (int i = 0; i < 8; i++) ones[i] = (bf16)1.0f;

  f32x4 o[2][4];
#pragma unroll
  for (int m = 0; m < 2; m++)
#pragma unroll
    for (int i = 0; i < 4; i++) o[m][i] = (f32x4){0.f, 0.f, 0.f, 0.f};
  f32x4 accl[2] = {(f32x4){0.f, 0.f, 0.f, 0.f}, (f32x4){0.f, 0.f, 0.f, 0.f}};

  int ktmax = qq >> 1;
  for (int kt = w; kt <= ktmax; kt += 4) {
    const bf16* Kg = K + (bhS + kt * 64) * DKH;
    bf16x8 kbf[8], vbf[8];
#pragma unroll
    for (int ns = 0; ns < 4; ns++)
#pragma unroll
      for (int ks = 0; ks < 2; ks++)
        kbf[ns * 2 + ks] = *(const bf16x8*)(Kg + (ns * 16 + ln) * DKH + ks * 32 + quad * 8);
#pragma unroll
    for (int ns = 0; ns < 4; ns++)
#pragma unroll
      for (int ks = 0; ks < 2; ks++)
        vbf[ns * 2 + ks] = *(const bf16x8*)(Vg0 + (size_t)(ns * 16 + ln) * SEQ + kt * 64 + ks * 32 + quad * 8);

    f32x4 s[2][4];
#pragma unroll
    for (int m = 0; m < 2; m++)
#pragma unroll
      for (int ns = 0; ns < 4; ns++) s[m][ns] = (f32x4){0.f, 0.f, 0.f, 0.f};
#pragma unroll
    for (int ns = 0; ns < 4; ns++)
#pragma unroll
      for (int m = 0; m < 2; m++) {
        s[m][ns] = __builtin_amdgcn_mfma_f32_16x16x32_bf16(qa[m][0], kbf[ns * 2], s[m][ns], 0, 0, 0);
        s[m][ns] = __builtin_amdgcn_mfma_f32_16x16x32_bf16(qa[m][1], kbf[ns * 2 + 1], s[m][ns], 0, 0, 0);
      }
    if (kt == ktmax) {
#pragma unroll
      for (int m = 0; m < 2; m++)
#pragma unroll
        for (int ns = 0; ns < 4; ns++)
#pragma unroll
          for (int r = 0; r < 4; r++) {
            int qrow = qbase + m * 16 + quad * 4 + r;
            int kpos = kt * 64 + ns * 16 + ln;
            if (kpos > qrow) s[m][ns][r] = -30000.f;
          }
    }
#pragma unroll
    for (int m = 0; m < 2; m++)
#pragma unroll
      for (int ns = 0; ns < 4; ns++)
#pragma unroll
        for (int r = 0; r < 4; r++)
          Pw[(m * 16 + quad * 4 + r) * LSTR + ns * 16 + ln] =
              (bf16)__builtin_amdgcn_exp2f(s[m][ns][r]);
    bf16x8 pa[2][2];
#pragma unroll
    for (int m = 0; m < 2; m++) {
      pa[m][0] = *(const bf16x8*)(Pw + (m * 16 + ln) * LSTR + quad * 8);
      pa[m][1] = *(const bf16x8*)(Pw + (m * 16 + ln) * LSTR + 32 + quad * 8);
    }
#pragma unroll
    for (int m = 0; m < 2; m++) {
      accl[m] = __builtin_amdgcn_mfma_f32_16x16x32_bf16(pa[m][0], ones, accl[m], 0, 0, 0);
      accl[m] = __builtin_amdgcn_mfma_f32_16x16x32_bf16(pa[m][1], ones, accl[m], 0, 0, 0);
    }
#pragma unroll
    for (int ns2 = 0; ns2 < 4; ns2++)
#pragma unroll
      for (int m = 0; m < 2; m++) {
        o[m][ns2] = __builtin_amdgcn_mfma_f32_16x16x32_bf16(pa[m][0], vbf[ns2 * 2], o[m][ns2], 0, 0, 0);
        o[m][ns2] = __builtin_amdgcn_mfma_f32_16x16x32_bf16(pa[m][1], vbf[ns2 * 2 + 1], o[m][ns2], 0, 0, 0);
      }
  }

  // ---- 2-pass combine in 18.4 KB union (P region dead after barrier) ----
  float* Ob = smem;                  // [2][32][OSTR] fp32
  float* Lb = smem + 2 * 32 * OSTR;  // [4][32]
  __syncthreads();
#pragma unroll
  for (int m = 0; m < 2; m++) {
    if (w < 2) {
#pragma unroll
      for (int ns2 = 0; ns2 < 4; ns2++)
#pragma unroll
        for (int r = 0; r < 4; r++)
          Ob[(w * 32 + m * 16 + quad * 4 + r) * OSTR + ns2 * 16 + ln] = o[m][ns2][r];
    }
    if (ln == 0) {
#pragma unroll
      for (int r = 0; r < 4; r++) Lb[w * 32 + m * 16 + quad * 4 + r] = accl[m][r];
    }
  }
  __syncthreads();
  if (w >= 2) {
#pragma unroll
    for (int m = 0; m < 2; m++)
#pragma unroll
      for (int ns2 = 0; ns2 < 4; ns2++)
#pragma unroll
        for (int r = 0; r < 4; r++) {
          int idx = ((w - 2) * 32 + m * 16 + quad * 4 + r) * OSTR + ns2 * 16 + ln;
          Ob[idx] += o[m][ns2][r];
        }
  }
  __syncthreads();

  int r = t >> 3, c0 = (t & 7) * 8;
  float l = Lb[r] + Lb[32 + r] + Lb[64 + r] + Lb[96 + r];
  float inv = 1.f / l;
  bf16 ov[8];
#pragma unroll
  for (int j = 0; j < 8; j++) {
    float v = Ob[r * OSTR + c0 + j] + Ob[(32 + r) * OSTR + c0 + j];
    ov[j] = (bf16)(v * inv);
  }
  int b = bh >> 4, h = bh & 15;
  *(uint4*)(out + ((size_t)b * SEQ + qbase + r) * DM + h * DKH + c0) = *(uint4*)ov;
}

// ---------------- Launch ----------------
extern "C" void kernel_launch(void* const* d_in, const int* in_sizes, int n_in,
                              void* d_out, int out_size, void* d_ws, size_t ws_size,
                              hipStream_t stream) {
  const float* x    = (const float*)d_in[0];
  // d_in[1] = mask (ignored; causal)
  const float* ln1g = (const float*)d_in[2];
  const float* ln1b = (const float*)d_in[3];
  const float* ln2g = (const float*)d_in[4];
  const float* ln2b = (const float*)d_in[5];
  const float* Wq = (const float*)d_in[6];   const float* bq = (const float*)d_in[7];
  const float* Wk = (const float*)d_in[8];   const float* bk = (const float*)d_in[9];
  const float* Wv = (const float*)d_in[10];  const float* bv = (const float*)d_in[11];
  const float* Wo = (const float*)d_in[12];  const float* bo = (const float*)d_in[13];
  const float* W1 = (const float*)d_in[14];  const float* b1 = (const float*)d_in[15];
  const float* W2 = (const float*)d_in[16];  const float* b2 = (const float*)d_in[17];
  float* outp = (float*)d_out;

  char* scratch = g_scratch ? g_scratch : (char*)d_ws;

  bf16* Wqt = (bf16*)scratch;                    // [3072][1024] contiguous = fused Bt
  bf16* Wkt = Wqt + (1 << 20);
  bf16* Wvt = Wkt + (1 << 20);
  bf16* Wot = Wvt + (1 << 20);
  bf16* W1t = Wot + (1 << 20);                   // 4M elems
  bf16* W2t = W1t + (4 << 20);                   // 4M elems
  bf16* normed = W2t + (4 << 20);                // 4M elems
  bf16* Qb = normed + (4 << 20);                 // Q,K,V contiguous (4M each)
  bf16* Kb = Qb + (4 << 20);
  bf16* Vb = Kb + (4 << 20);
  bf16* Vtb = Vb + (4 << 20);
  bf16* attn_o = Vtb + (4 << 20);                // 4M elems
  float* resf = (float*)(attn_o + (4 << 20));    // 4M floats
  float* bias_cat = resf + (4 << 20);            // 3072 floats
  bf16* h1 = Qb;                                 // alias: Q/K/V/Vt dead after attention

  dim3 b256(256), b1k(32, 32);

  ln_kernel<<<NROWS, b256, 0, stream>>>(x, ln1g, ln1b, normed);
  concat_bias<<<12, b256, 0, stream>>>(bq, bk, bv, bias_cat);

  transpose_f32_bf16<<<dim3(32, 32), b1k, 0, stream>>>(Wq, Wqt, 1024, 1024);
  transpose_f32_bf16<<<dim3(32, 32), b1k, 0, stream>>>(Wk, Wkt, 1024, 1024);
  transpose_f32_bf16<<<dim3(32, 32), b1k, 0, stream>>>(Wv, Wvt, 1024, 1024);
  transpose_f32_bf16<<<dim3(32, 32), b1k, 0, stream>>>(Wo, Wot, 1024, 1024);
  transpose_f32_bf16<<<dim3(128, 32), b1k, 0, stream>>>(W1, W1t, 1024, 4096);
  transpose_f32_bf16<<<dim3(32, 128), b1k, 0, stream>>>(W2, W2t, 4096, 1024);

  // fused QKV: N=3072, Bt = Wqt|Wkt|Wvt rows, 24x32 = 768 blocks (3/CU)
  gemm_bt<EPI_QKV3, 128><<<dim3(24, 32), b256, 0, stream>>>(
      normed, Wqt, bias_cat, 1024, 3072, Qb, nullptr, nullptr);

  transpose_bf16<<<dim3(2, 64, 32), b1k, 0, stream>>>(Vb, Vtb, 2048, 64);

  attn_kernel<<<dim3(2048), b256, 0, stream>>>(Qb, Kb, Vtb, attn_o);

  gemm_bt<EPI_ATTN_RES, 64><<<dim3(16, 32), b256, 0, stream>>>(
      attn_o, Wot, bo, 1024, 1024, nullptr, resf, x);

  ln_kernel<<<NROWS, b256, 0, stream>>>(resf, ln2g, ln2b, normed);

  gemm_bt<EPI_GELU, 128><<<dim3(32, 32), b256, 0, stream>>>(
      normed, W1t, b1, 1024, 4096, h1, nullptr, nullptr);

  gemm_bt<EPI_FFN2, 64><<<dim3(16, 32), b256, 0, stream>>>(
      h1, W2t, b2, 4096, 1024, nullptr, outp, resf);
}

// Round 10
// 401.486 us; speedup vs baseline: 1.7237x; 1.7237x over previous
//
#include <hip/hip_runtime.h>

// Round 10: revert K-loop to R8 (BK=64 + XOR swizzle + global_load_lds; R9's
// LDS-free variant thrashed L2, FETCH 37->149MB). Rebuild epilogues: LDS-
// transposed coalesced stores (4-16 vector stores/thread instead of 64
// scattered), coalesced residual loads, tanh-form exp2 GELU (~8 ops vs ~25
// for erff). Attention (R8 split-K + XCD swizzle) unchanged.

typedef __bf16 bf16;
typedef __bf16 bf16x8 __attribute__((ext_vector_type(8)));
typedef float f32x4 __attribute__((ext_vector_type(4)));

#define NROWS 4096   // B*S
#define DM 1024
#define SEQ 2048
#define NHEAD 16
#define DKH 64
#define DFF 4096
#define QSCALE 0.18033688f   // 0.125 * log2(e), folded into Q at QKV epilogue

#define GLL16(gptr, lptr) \
  __builtin_amdgcn_global_load_lds((const __attribute__((address_space(1))) void*)(gptr), \
                                   (__attribute__((address_space(3))) void*)(lptr), 16, 0, 0)

// ---------------- private scratch (allocated at dlopen, NOT inside kernel_launch) ----
static char* g_scratch = nullptr;
namespace {
struct ScratchInit {
  ScratchInit() {
    void* p = nullptr;
    if (hipMalloc(&p, (size_t)128 * 1024 * 1024) == hipSuccess) g_scratch = (char*)p;
  }
};
static ScratchInit g_scratch_init;
}

// ---------------- LayerNorm (fp32 in, bf16 out) ----------------
__global__ __launch_bounds__(256) void ln_kernel(const float* __restrict__ inp,
                                                 const float* __restrict__ gamma,
                                                 const float* __restrict__ beta,
                                                 bf16* __restrict__ out) {
  int row = blockIdx.x;
  int t = threadIdx.x;
  float4 xv = *((const float4*)(inp + (size_t)row * DM) + t);
  float v[4] = {xv.x, xv.y, xv.z, xv.w};
  float s = 0.f, sq = 0.f;
#pragma unroll
  for (int i = 0; i < 4; i++) { s += v[i]; sq += v[i] * v[i]; }
#pragma unroll
  for (int m = 32; m >= 1; m >>= 1) { s += __shfl_xor(s, m); sq += __shfl_xor(sq, m); }
  __shared__ float rs[4], rq[4];
  int w = t >> 6, lane = t & 63;
  if (lane == 0) { rs[w] = s; rq[w] = sq; }
  __syncthreads();
  s = rs[0] + rs[1] + rs[2] + rs[3];
  sq = rq[0] + rq[1] + rq[2] + rq[3];
  float mu = s * (1.f / DM);
  float var = sq * (1.f / DM) - mu * mu;
  float rinv = rsqrtf(var + 1e-5f);
  float4 gv = *((const float4*)gamma + t);
  float4 bv = *((const float4*)beta + t);
  float g[4] = {gv.x, gv.y, gv.z, gv.w}, b[4] = {bv.x, bv.y, bv.z, bv.w};
  bf16 ov[4];
#pragma unroll
  for (int i = 0; i < 4; i++) ov[i] = (bf16)((v[i] - mu) * rinv * g[i] + b[i]);
  *(uint2*)(out + (size_t)row * DM + t * 4) = *(uint2*)ov;
}

// ---------------- bias concat (bq|bk|bv -> 3072 floats) ----------------
__global__ __launch_bounds__(256) void concat_bias(const float* __restrict__ bq,
                                                   const float* __restrict__ bk,
                                                   const float* __restrict__ bv,
                                                   float* __restrict__ cat) {
  int i = blockIdx.x * 256 + threadIdx.x;
  float v = (i < 1024) ? bq[i] : (i < 2048 ? bk[i - 1024] : bv[i - 2048]);
  cat[i] = v;
}

// ---------------- Transpose fp32 [R][C] -> bf16 [C][R] ----------------
__global__ __launch_bounds__(1024) void transpose_f32_bf16(const float* __restrict__ in,
                                                           bf16* __restrict__ out,
                                                           int R, int C) {
  __shared__ bf16 tile[32][33];
  int x = blockIdx.x * 32 + threadIdx.x;
  int y = blockIdx.y * 32 + threadIdx.y;
  tile[threadIdx.y][threadIdx.x] = (bf16)in[(size_t)y * C + x];
  __syncthreads();
  int ox = blockIdx.y * 32 + threadIdx.x;
  int oy = blockIdx.x * 32 + threadIdx.y;
  out[(size_t)oy * R + ox] = tile[threadIdx.x][threadIdx.y];
}

// ---------------- Transpose bf16 [R][C] -> bf16 [C][R] (for V) ----------------
__global__ __launch_bounds__(1024) void transpose_bf16(const bf16* __restrict__ in,
                                                       bf16* __restrict__ out,
                                                       int R, int C) {
  __shared__ bf16 tile[32][33];
  size_t zoff = (size_t)blockIdx.z * (size_t)R * (size_t)C;
  int x = blockIdx.x * 32 + threadIdx.x;
  int y = blockIdx.y * 32 + threadIdx.y;
  tile[threadIdx.y][threadIdx.x] = in[zoff + (size_t)y * C + x];
  __syncthreads();
  int ox = blockIdx.y * 32 + threadIdx.x;
  int oy = blockIdx.x * 32 + threadIdx.y;
  out[zoff + (size_t)oy * R + ox] = tile[threadIdx.x][threadIdx.y];
}

// ---------------- GEMM: C[M][N] = A[M][K] * Bt[N][K]^T + bias, fused epilogues ----------
// K-loop: BK=64, XOR-swizzled LDS (R8). Epilogue: LDS-transposed coalesced stores.
#define BM 128
#define BK 64
#define ESTR 68   // fp32 epilogue LDS row stride (words)

#define EPI_QKV3 0      // fused QKV: bf16 -> [B,H,S,DKH] x3, Q scaled by QSCALE
#define EPI_ATTN_RES 1  // outf fp32 = acc + bias + add (x fp32)
#define EPI_GELU 2      // outb bf16 = gelu(acc + bias)
#define EPI_FFN2 3      // outf fp32 = acc + bias + add (res fp32)

// BNT = 128: waves 2x2 (64x64 each), MS=4. BNT = 64: waves 4x1 (32x64), MS=2.
template<int EPI, int BNT>
__global__ __launch_bounds__(256, 2) void gemm_bt(
    const bf16* __restrict__ A, const bf16* __restrict__ Bt,
    const float* __restrict__ bias, int Kd, int N,
    bf16* __restrict__ outb, float* __restrict__ outf,
    const float* __restrict__ add) {
  constexpr int MS = (BNT == 128) ? 4 : 2;
  __shared__ __align__(16) char smem[34816];  // max(As+Bs 32KB, epi 4*32*68*4B)
  bf16* As = (bf16*)smem;
  bf16* Bs = As + BM * BK;
  int t = threadIdx.x;
  int m0 = blockIdx.y * BM, n0 = blockIdx.x * BNT;
  int w = t >> 6, lane = t & 63, ln = lane & 15, quad = lane >> 4;
  int wm = (BNT == 128) ? (w >> 1) * 64 : w * 32;
  int wn = (BNT == 128) ? (w & 1) * 64 : 0;
  f32x4 acc[MS][4];
#pragma unroll
  for (int i = 0; i < MS; i++)
#pragma unroll
    for (int j = 0; j < 4; j++) acc[i][j] = (f32x4){0.f, 0.f, 0.f, 0.f};

  int lr = (t >> 3) & 7, lc = t & 7;
  int gcolsw = ((lc ^ lr) * 8);
  const bf16* Ab = A + (size_t)(m0 + w * 8 + lr) * Kd + gcolsw;
  const bf16* Bb = Bt + (size_t)(n0 + w * 8 + lr) * Kd + gcolsw;
  bf16* AsW = As + (w * 8) * BK;  // wave-uniform base; HW appends lane*16B
  bf16* BsW = Bs + (w * 8) * BK;

  for (int k0 = 0; k0 < Kd; k0 += BK) {
    __syncthreads();  // previous iteration's fragment reads complete
#pragma unroll
    for (int j = 0; j < 4; j++)
      GLL16(Ab + (size_t)(32 * j) * Kd + k0, AsW + 32 * j * BK);
#pragma unroll
    for (int j = 0; j < BNT / 32; j++)
      GLL16(Bb + (size_t)(32 * j) * Kd + k0, BsW + 32 * j * BK);
    __syncthreads();  // drains vmcnt -> staged data visible
#pragma unroll
    for (int kk = 0; kk < 2; kk++) {
      bf16x8 af[MS], bfr[4];
#pragma unroll
      for (int ms = 0; ms < MS; ms++) {
        int r = wm + ms * 16 + ln;
        af[ms] = *(const bf16x8*)(As + r * BK + (((kk * 4 + quad) ^ (r & 7)) * 8));
      }
#pragma unroll
      for (int ns = 0; ns < 4; ns++) {
        int r = wn + ns * 16 + ln;
        bfr[ns] = *(const bf16x8*)(Bs + r * BK + (((kk * 4 + quad) ^ (r & 7)) * 8));
      }
#pragma unroll
      for (int ms = 0; ms < MS; ms++)
#pragma unroll
        for (int ns = 0; ns < 4; ns++)
          acc[ms][ns] = __builtin_amdgcn_mfma_f32_16x16x32_bf16(af[ms], bfr[ns], acc[ms][ns], 0, 0, 0);
    }
  }

  // ---- epilogue: per-wave LDS transpose -> coalesced vector stores ----
  __syncthreads();  // staging LDS dead; reuse as fp32 transpose buffer
  float* Ew = (float*)smem + w * (32 * ESTR);
  int erow = lane >> 1;            // 0..31
  int ec0 = (lane & 1) * 32;       // 0 / 32
  constexpr int HALVES = (BNT == 128) ? 2 : 1;
#pragma unroll
  for (int half = 0; half < HALVES; half++) {
#pragma unroll
    for (int msl = 0; msl < 2; msl++) {
      int ms = half * 2 + msl;
#pragma unroll
      for (int ns = 0; ns < 4; ns++) {
        float bv = bias[n0 + wn + ns * 16 + ln];
#pragma unroll
        for (int r = 0; r < 4; r++)
          Ew[(msl * 16 + quad * 4 + r) * ESTR + ns * 16 + ln] = acc[ms][ns][r] + bv;
      }
    }
    // same-wave read-after-write; compiler inserts lgkmcnt wait
    int grow = m0 + wm + half * 32 + erow;
    int gcol = n0 + wn + ec0;
    float v[32];
#pragma unroll
    for (int j = 0; j < 8; j++) {
      float4 tv = *(const float4*)(Ew + erow * ESTR + ec0 + j * 4);
      v[j * 4 + 0] = tv.x; v[j * 4 + 1] = tv.y; v[j * 4 + 2] = tv.z; v[j * 4 + 3] = tv.w;
    }
    if (EPI == EPI_QKV3) {
      int which = gcol >> 10, cc = gcol & 1023;
      int h = cc >> 6, dk0 = cc & 63;
      float sc = (which == 0) ? QSCALE : 1.f;
      int b = grow >> 11, sx = grow & 2047;
      bf16 ov[32];
#pragma unroll
      for (int j = 0; j < 32; j++) ov[j] = (bf16)(v[j] * sc);
      bf16* dst = outb + (size_t)which * (4 << 20) +
                  ((((size_t)b * NHEAD + h) * SEQ) + sx) * DKH + dk0;
#pragma unroll
      for (int j = 0; j < 4; j++) *(uint4*)(dst + j * 8) = *(uint4*)(ov + j * 8);
    } else if (EPI == EPI_GELU) {
      // gelu(x) ~= x*u/(1+u), u = exp2(x*(C1 + C2*x^2))  (tanh form)
      bf16 ov[32];
#pragma unroll
      for (int j = 0; j < 32; j++) {
        float x = v[j];
        float u = __builtin_amdgcn_exp2f(x * fmaf(0.102944f, x * x, 2.3021204f));
        ov[j] = (bf16)(x * u * __builtin_amdgcn_rcpf(1.f + u));
      }
      bf16* dst = outb + (size_t)grow * N + gcol;
#pragma unroll
      for (int j = 0; j < 4; j++) *(uint4*)(dst + j * 8) = *(uint4*)(ov + j * 8);
    } else {  // EPI_ATTN_RES / EPI_FFN2: fp32 out = val + add
      const float* ap = add + (size_t)grow * DM + gcol;
      float* op = outf + (size_t)grow * DM + gcol;
#pragma unroll
      for (int j = 0; j < 8; j++) {
        float4 av = *(const float4*)(ap + j * 4);
        float4 o4 = {v[j * 4 + 0] + av.x, v[j * 4 + 1] + av.y,
                     v[j * 4 + 2] + av.z, v[j * 4 + 3] + av.w};
        *(float4*)(op + j * 4) = o4;
      }
    }
  }
}

// ---------------- Flash attention, split-K, XCD-swizzled, 2-pass combine (R8) ----------
#define LSTR 72
#define OSTR 68   // fp32 combine row stride (2-way conflicts only)

__global__ __launch_bounds__(256) void attn_kernel(
    const bf16* __restrict__ Q, const bf16* __restrict__ K,
    const bf16* __restrict__ Vt, bf16* __restrict__ out) {
  __shared__ float smem[4608];  // 18432 B: max(P 4*32*72*2B, Ob 2*32*68*4B + Lb 512B)
  int lin = blockIdx.x;
  int bh = lin & 31;
  int qq = 63 - (lin >> 5);            // LPT: heaviest first
  int t = threadIdx.x, w = t >> 6, lane = t & 63, ln = lane & 15, quad = lane >> 4;
  int qbase = qq * 32;
  size_t bhS = (size_t)bh * SEQ;
  const bf16* Vg0 = Vt + (size_t)bh * DKH * SEQ;
  bf16* Pw = (bf16*)smem + w * 32 * LSTR;   // per-wave P slice (loop only)

  bf16x8 qa[2][2];
#pragma unroll
  for (int m = 0; m < 2; m++)
#pragma unroll
    for (int ks = 0; ks < 2; ks++)
      qa[m][ks] = *(const bf16x8*)(Q + (bhS + qbase + m * 16 + ln) * DKH + ks * 32 + quad * 8);

  bf16x8 ones;
#pragma unroll
  for (int i = 0; i < 8; i++) ones[i] = (bf16)1.0f;

  f32x4 o[2][4];
#pragma unroll
  for (int m = 0; m < 2; m++)
#pragma unroll
    for (int i = 0; i < 4; i++) o[m][i] = (f32x4){0.f, 0.f, 0.f, 0.f};
  f32x4 accl[2] = {(f32x4){0.f, 0.f, 0.f, 0.f}, (f32x4){0.f, 0.f, 0.f, 0.f}};

  int ktmax = qq >> 1;
  for (int kt = w; kt <= ktmax; kt += 4) {
    const bf16* Kg = K + (bhS + kt * 64) * DKH;
    bf16x8 kbf[8], vbf[8];
#pragma unroll
    for (int ns = 0; ns < 4; ns++)
#pragma unroll
      for (int ks = 0; ks < 2; ks++)
        kbf[ns * 2 + ks] = *(const bf16x8*)(Kg + (ns * 16 + ln) * DKH + ks * 32 + quad * 8);
#pragma unroll
    for (int ns = 0; ns < 4; ns++)
#pragma unroll
      for (int ks = 0; ks < 2; ks++)
        vbf[ns * 2 + ks] = *(const bf16x8*)(Vg0 + (size_t)(ns * 16 + ln) * SEQ + kt * 64 + ks * 32 + quad * 8);

    f32x4 s[2][4];
#pragma unroll
    for (int m = 0; m < 2; m++)
#pragma unroll
      for (int ns = 0; ns < 4; ns++) s[m][ns] = (f32x4){0.f, 0.f, 0.f, 0.f};
#pragma unroll
    for (int ns = 0; ns < 4; ns++)
#pragma unroll
      for (int m = 0; m < 2; m++) {
        s[m][ns] = __builtin_amdgcn_mfma_f32_16x16x32_bf16(qa[m][0], kbf[ns * 2], s[m][ns], 0, 0, 0);
        s[m][ns] = __builtin_amdgcn_mfma_f32_16x16x32_bf16(qa[m][1], kbf[ns * 2 + 1], s[m][ns], 0, 0, 0);
      }
    if (kt == ktmax) {
#pragma unroll
      for (int m = 0; m < 2; m++)
#pragma unroll
        for (int ns = 0; ns < 4; ns++)
#pragma unroll
          for (int r = 0; r < 4; r++) {
            int qrow = qbase + m * 16 + quad * 4 + r;
            int kpos = kt * 64 + ns * 16 + ln;
            if (kpos > qrow) s[m][ns][r] = -30000.f;
          }
    }
#pragma unroll
    for (int m = 0; m < 2; m++)
#pragma unroll
      for (int ns = 0; ns < 4; ns++)
#pragma unroll
        for (int r = 0; r < 4; r++)
          Pw[(m * 16 + quad * 4 + r) * LSTR + ns * 16 + ln] =
              (bf16)__builtin_amdgcn_exp2f(s[m][ns][r]);
    bf16x8 pa[2][2];
#pragma unroll
    for (int m = 0; m < 2; m++) {
      pa[m][0] = *(const bf16x8*)(Pw + (m * 16 + ln) * LSTR + quad * 8);
      pa[m][1] = *(const bf16x8*)(Pw + (m * 16 + ln) * LSTR + 32 + quad * 8);
    }
#pragma unroll
    for (int m = 0; m < 2; m++) {
      accl[m] = __builtin_amdgcn_mfma_f32_16x16x32_bf16(pa[m][0], ones, accl[m], 0, 0, 0);
      accl[m] = __builtin_amdgcn_mfma_f32_16x16x32_bf16(pa[m][1], ones, accl[m], 0, 0, 0);
    }
#pragma unroll
    for (int ns2 = 0; ns2 < 4; ns2++)
#pragma unroll
      for (int m = 0; m < 2; m++) {
        o[m][ns2] = __builtin_amdgcn_mfma_f32_16x16x32_bf16(pa[m][0], vbf[ns2 * 2], o[m][ns2], 0, 0, 0);
        o[m][ns2] = __builtin_amdgcn_mfma_f32_16x16x32_bf16(pa[m][1], vbf[ns2 * 2 + 1], o[m][ns2], 0, 0, 0);
      }
  }

  // ---- 2-pass combine in 18.4 KB union (P region dead after barrier) ----
  float* Ob = smem;                  // [2][32][OSTR] fp32
  float* Lb = smem + 2 * 32 * OSTR;  // [4][32]
  __syncthreads();
#pragma unroll
  for (int m = 0; m < 2; m++) {
    if (w < 2) {
#pragma unroll
      for (int ns2 = 0; ns2 < 4; ns2++)
#pragma unroll
        for (int r = 0; r < 4; r++)
          Ob[(w * 32 + m * 16 + quad * 4 + r) * OSTR + ns2 * 16 + ln] = o[m][ns2][r];
    }
    if (ln == 0) {
#pragma unroll
      for (int r = 0; r < 4; r++) Lb[w * 32 + m * 16 + quad * 4 + r] = accl[m][r];
    }
  }
  __syncthreads();
  if (w >= 2) {
#pragma unroll
    for (int m = 0; m < 2; m++)
#pragma unroll
      for (int ns2 = 0; ns2 < 4; ns2++)
#pragma unroll
        for (int r = 0; r < 4; r++) {
          int idx = ((w - 2) * 32 + m * 16 + quad * 4 + r) * OSTR + ns2 * 16 + ln;
          Ob[idx] += o[m][ns2][r];
        }
  }
  __syncthreads();

  int r = t >> 3, c0 = (t & 7) * 8;
  float l = Lb[r] + Lb[32 + r] + Lb[64 + r] + Lb[96 + r];
  float inv = 1.f / l;
  bf16 ov[8];
#pragma unroll
  for (int j = 0; j < 8; j++) {
    float v = Ob[r * OSTR + c0 + j] + Ob[(32 + r) * OSTR + c0 + j];
    ov[j] = (bf16)(v * inv);
  }
  int b = bh >> 4, h = bh & 15;
  *(uint4*)(out + ((size_t)b * SEQ + qbase + r) * DM + h * DKH + c0) = *(uint4*)ov;
}

// ---------------- Launch ----------------
extern "C" void kernel_launch(void* const* d_in, const int* in_sizes, int n_in,
                              void* d_out, int out_size, void* d_ws, size_t ws_size,
                              hipStream_t stream) {
  const float* x    = (const float*)d_in[0];
  // d_in[1] = mask (ignored; causal)
  const float* ln1g = (const float*)d_in[2];
  const float* ln1b = (const float*)d_in[3];
  const float* ln2g = (const float*)d_in[4];
  const float* ln2b = (const float*)d_in[5];
  const float* Wq = (const float*)d_in[6];   const float* bq = (const float*)d_in[7];
  const float* Wk = (const float*)d_in[8];   const float* bk = (const float*)d_in[9];
  const float* Wv = (const float*)d_in[10];  const float* bv = (const float*)d_in[11];
  const float* Wo = (const float*)d_in[12];  const float* bo = (const float*)d_in[13];
  const float* W1 = (const float*)d_in[14];  const float* b1 = (const float*)d_in[15];
  const float* W2 = (const float*)d_in[16];  const float* b2 = (const float*)d_in[17];
  float* outp = (float*)d_out;

  char* scratch = g_scratch ? g_scratch : (char*)d_ws;

  bf16* Wqt = (bf16*)scratch;                    // [3072][1024] contiguous = fused Bt
  bf16* Wkt = Wqt + (1 << 20);
  bf16* Wvt = Wkt + (1 << 20);
  bf16* Wot = Wvt + (1 << 20);
  bf16* W1t = Wot + (1 << 20);                   // 4M elems
  bf16* W2t = W1t + (4 << 20);                   // 4M elems
  bf16* normed = W2t + (4 << 20);                // 4M elems
  bf16* Qb = normed + (4 << 20);                 // Q,K,V contiguous (4M each)
  bf16* Kb = Qb + (4 << 20);
  bf16* Vb = Kb + (4 << 20);
  bf16* Vtb = Vb + (4 << 20);
  bf16* attn_o = Vtb + (4 << 20);                // 4M elems
  float* resf = (float*)(attn_o + (4 << 20));    // 4M floats
  float* bias_cat = resf + (4 << 20);            // 3072 floats
  bf16* h1 = Qb;                                 // alias: Q/K/V/Vt dead after attention

  dim3 b256(256), b1k(32, 32);

  ln_kernel<<<NROWS, b256, 0, stream>>>(x, ln1g, ln1b, normed);
  concat_bias<<<12, b256, 0, stream>>>(bq, bk, bv, bias_cat);

  transpose_f32_bf16<<<dim3(32, 32), b1k, 0, stream>>>(Wq, Wqt, 1024, 1024);
  transpose_f32_bf16<<<dim3(32, 32), b1k, 0, stream>>>(Wk, Wkt, 1024, 1024);
  transpose_f32_bf16<<<dim3(32, 32), b1k, 0, stream>>>(Wv, Wvt, 1024, 1024);
  transpose_f32_bf16<<<dim3(32, 32), b1k, 0, stream>>>(Wo, Wot, 1024, 1024);
  transpose_f32_bf16<<<dim3(128, 32), b1k, 0, stream>>>(W1, W1t, 1024, 4096);
  transpose_f32_bf16<<<dim3(32, 128), b1k, 0, stream>>>(W2, W2t, 4096, 1024);

  // fused QKV: N=3072, Bt = Wqt|Wkt|Wvt rows, 24x32 = 768 blocks (3/CU)
  gemm_bt<EPI_QKV3, 128><<<dim3(24, 32), b256, 0, stream>>>(
      normed, Wqt, bias_cat, 1024, 3072, Qb, nullptr, nullptr);

  transpose_bf16<<<dim3(2, 64, 32), b1k, 0, stream>>>(Vb, Vtb, 2048, 64);

  attn_kernel<<<dim3(2048), b256, 0, stream>>>(Qb, Kb, Vtb, attn_o);

  gemm_bt<EPI_ATTN_RES, 64><<<dim3(16, 32), b256, 0, stream>>>(
      attn_o, Wot, bo, 1024, 1024, nullptr, resf, x);

  ln_kernel<<<NROWS, b256, 0, stream>>>(resf, ln2g, ln2b, normed);

  gemm_bt<EPI_GELU, 128><<<dim3(32, 32), b256, 0, stream>>>(
      normed, W1t, b1, 1024, 4096, h1, nullptr, nullptr);

  gemm_bt<EPI_FFN2, 64><<<dim3(16, 32), b256, 0, stream>>>(
      h1, W2t, b2, 4096, 1024, nullptr, outp, resf);
}